// Round 18
// baseline (188.263 us; speedup 1.0000x reference)
//
#include <hip/hip_runtime.h>
#include <hip/hip_bf16.h>

// RelationalKENN, R15 (resubmit; R17-round bench was a broker timeout).
// Continue confirmed direction -- EPB 4096->8192.
//
// History: R5 bucket sort + LDS binning. R6-R8 block-private 8B-record
// slabs: edge 102->56us. R9 occupancy probe: edge FLAT (insensitive).
// R10 LDS-staged coalesced rec stores: 159.6. R11 nontemporal: NULL.
// R12 fused cooperative: CATASTROPHIC (grid.sync across 8 XCD L2s).
// R13 NSLICE 16->8: FLAT (bin+merge not BW-bound). R14 EPB 1024->4096:
// 153.2 BEST (edge 48->44, bin segment-latency theory partially
// confirmed; occupancy 33% reconfirms edge occupancy-insensitive).
// R15: EPB 8192 (1024thr x 8 edges, 128KB LDS stage -- gfx950 allows
// 160KB/wg). Segments ~630 records (~10 iters/descriptor), descriptor
// stalls halve again; edge grid 245 blocks ~ 1/CU single wave.
// Predict: edge 44+-3 flat; total ->146-150 if bin latency continues to
// pay; flat >=152 -> knob exhausted, structural floor reached.
//
// Layout: d_out = [ up : n_nodes*16 fp32 | bp : n_edges*4 fp32 ]
// ws = [ recs | partials | u4 | cnts | offs ]

#define NRANGE 13
#define RBITS  13
#define RSIZE  8192            // nodes per range (1 << RBITS)
#define NSLICE 16
#define EPB    8192            // edges per block (1024 threads x 8)
#define SEGCAP 8192            // records per side per block slab
#define FXP_SCALE 2048.0f      // 2^11; magnitudes <= 0.5 -> q <= 1024 (11b)
#define FXP_INV   (1.0f / 2048.0f)

__device__ __forceinline__ void sm2(float xi, float xj, float w,
                                    float& di, float& dj) {
    float na = -xi, b = xj;
    float m  = fmaxf(na, b);
    float e0 = __expf(na - m), e1 = __expf(b - m);
    float inv = w / (e0 + e1);
    di -= e0 * inv;
    dj += e1 * inv;
}

__device__ __forceinline__ void sm3(float xi, float xj, float xk, float w,
                                    float& di, float& dj, float& dk) {
    float na = -xi, b = xj, c = xk;
    float m  = fmaxf(fmaxf(na, b), c);
    float e0 = __expf(na - m), e1 = __expf(b - m), e2 = __expf(c - m);
    float inv = w / (e0 + e1 + e2);
    di -= e0 * inv;
    dj += e1 * inv;
    dk += e2 * inv;
}

__global__ void unary_kernel(const float* __restrict__ x_in,
                             const float* __restrict__ uw,
                             float* __restrict__ up,
                             float4* __restrict__ u4,      // compact cols 0..3
                             int n_nodes) {
    int n = blockIdx.x * blockDim.x + threadIdx.x;
    if (n >= n_nodes) return;

    const float4* xr = (const float4*)(x_in + (size_t)n * 16);
    float4 r0 = xr[0], r1 = xr[1], r2 = xr[2], r3 = xr[3];
    float x[16] = {r0.x, r0.y, r0.z, r0.w,
                   r1.x, r1.y, r1.z, r1.w,
                   r2.x, r2.y, r2.z, r2.w,
                   r3.x, r3.y, r3.z, r3.w};
    float d[16];
#pragma unroll
    for (int i = 0; i < 16; ++i) d[i] = 0.0f;

    sm2(x[0],  x[1],          uw[0], d[0],  d[1]);
    sm2(x[1],  x[2],          uw[1], d[1],  d[2]);
    sm3(x[2],  x[3],  x[4],   uw[2], d[2],  d[3],  d[4]);
    sm2(x[4],  x[5],          uw[3], d[4],  d[5]);
    sm3(x[6],  x[7],  x[8],   uw[4], d[6],  d[7],  d[8]);
    sm2(x[8],  x[9],          uw[5], d[8],  d[9]);
    sm3(x[10], x[11], x[12],  uw[6], d[10], d[11], d[12]);
    sm3(x[13], x[14], x[15],  uw[7], d[13], d[14], d[15]);

    float4* w_up = (float4*)(up + (size_t)n * 16);
    float4 v0 = make_float4(x[0] + d[0], x[1] + d[1], x[2] + d[2], x[3] + d[3]);
    w_up[0] = v0;
#pragma unroll
    for (int i = 1; i < 4; ++i)
        w_up[i] = make_float4(x[4*i]   + d[4*i],   x[4*i+1] + d[4*i+1],
                              x[4*i+2] + d[4*i+2], x[4*i+3] + d[4*i+3]);
    u4[n] = v0;
}

// ---------- fast path ----------

__global__ __launch_bounds__(1024, 4)
void edge_compute_kernel(const float4* __restrict__ u4,
                         const float4* __restrict__ binary,
                         const int* __restrict__ idx1,
                         const int* __restrict__ idx2,
                         const float* __restrict__ bw,
                         unsigned long long* __restrict__ recs, // [blk][2][SEGCAP]
                         unsigned* __restrict__ cnts,           // [blk][2][NRANGE]
                         unsigned* __restrict__ offs,           // [blk][2][NRANGE]
                         float4* __restrict__ bp,
                         int n_edges) {
    __shared__ unsigned cnt[2][NRANGE];
    __shared__ unsigned off[2][NRANGE];
    __shared__ __align__(16) unsigned long long stage[2][SEGCAP];  // 128 KB
    int tid = threadIdx.x;
    if (tid < 2 * NRANGE) ((unsigned*)cnt)[tid] = 0;
    __syncthreads();

    float w[4] = {bw[0], bw[1], bw[2], bw[3]};

    int e[8]; bool valid[8];
    int i1[8], i2[8], r1[8], r2[8];
    unsigned rank1[8], rank2[8];
    unsigned long long q1[8], q2[8];
    float4 dbv4[8];

#pragma unroll
    for (int k = 0; k < 8; ++k) {
        e[k] = blockIdx.x * EPB + k * 1024 + tid;
        valid[k] = e[k] < n_edges;
        int ec = valid[k] ? e[k] : 0;
        i1[k] = idx1[ec];
        i2[k] = idx2[ec];
    }
#pragma unroll
    for (int k = 0; k < 8; ++k) {
        float4 a4 = u4[i1[k]];             // gathers + stream, 3 loads/k in flight
        float4 c4 = u4[i2[k]];
        float4 b4 = binary[valid[k] ? e[k] : 0];
        float a[4]  = {a4.x, a4.y, a4.z, a4.w};
        float bb[4] = {b4.x, b4.y, b4.z, b4.w};
        float c[4]  = {c4.x, c4.y, c4.z, c4.w};
        unsigned p1[4], p2[4];
        float dbv[4];
#pragma unroll
        for (int i = 0; i < 4; ++i) {
            // clause ([i, 32+i, 16+i], [-1,-1,+1]): sel = [-u1_i, -b_i, u2_i]
            float na = -a[i], nb = -bb[i], cc = c[i];
            float m  = fmaxf(fmaxf(na, nb), cc);
            float e0 = __expf(na - m), e1 = __expf(nb - m), e2 = __expf(cc - m);
            float inv = w[i] / (e0 + e1 + e2);
            p1[i]  = __float2uint_rn(e0 * inv * FXP_SCALE);  // |du1|
            p2[i]  = __float2uint_rn(e2 * inv * FXP_SCALE);  // du2
            dbv[i] = bb[i] - e1 * inv;
        }
        q1[k] = (unsigned long long)(unsigned)(i1[k] & (RSIZE - 1))
              | ((unsigned long long)p1[0] << 13) | ((unsigned long long)p1[1] << 25)
              | ((unsigned long long)p1[2] << 37) | ((unsigned long long)p1[3] << 49);
        q2[k] = (unsigned long long)(unsigned)(i2[k] & (RSIZE - 1))
              | ((unsigned long long)p2[0] << 13) | ((unsigned long long)p2[1] << 25)
              | ((unsigned long long)p2[2] << 37) | ((unsigned long long)p2[3] << 49);
        dbv4[k] = make_float4(dbv[0], dbv[1], dbv[2], dbv[3]);
        r1[k] = i1[k] >> RBITS;
        r2[k] = i2[k] >> RBITS;
        if (valid[k]) {
            rank1[k] = atomicAdd(&cnt[0][r1[k]], 1u);   // LDS atomic rank
            rank2[k] = atomicAdd(&cnt[1][r2[k]], 1u);
        }
    }
    __syncthreads();
    if (tid < 2) {                          // 13-entry exclusive scan per side
        unsigned acc = 0;
#pragma unroll
        for (int r = 0; r < NRANGE; ++r) { off[tid][r] = acc; acc += cnt[tid][r]; }
    }
    __syncthreads();
    if (tid < 2 * NRANGE) {                 // publish counts + offsets
        cnts[(size_t)blockIdx.x * 2 * NRANGE + tid] = ((unsigned*)cnt)[tid];
        offs[(size_t)blockIdx.x * 2 * NRANGE + tid] = ((unsigned*)off)[tid];
    }
#pragma unroll
    for (int k = 0; k < 8; ++k) {           // rank-scatter into LDS stage
        if (!valid[k]) continue;
        stage[0][off[0][r1[k]] + rank1[k]] = q1[k];
        stage[1][off[1][r2[k]] + rank2[k]] = q2[k];
        bp[e[k]] = dbv4[k];
    }
    __syncthreads();
    // stream slab out fully coalesced: 1024 thr x 8 x 16B
    ulonglong2* dst = (ulonglong2*)(recs + (size_t)blockIdx.x * 2 * SEGCAP);
    const ulonglong2* s0 = (const ulonglong2*)stage[0];
    const ulonglong2* s1 = (const ulonglong2*)stage[1];
#pragma unroll
    for (int j = 0; j < 4; ++j) {
        dst[j * 1024 + tid]        = s0[j * 1024 + tid];
        dst[4096 + j * 1024 + tid] = s1[j * 1024 + tid];
    }
}

__global__ __launch_bounds__(1024)
void bin_kernel(const unsigned long long* __restrict__ recs,
                const unsigned* __restrict__ cnts,
                const unsigned* __restrict__ offs,
                unsigned long long* __restrict__ partials,
                int nblk) {
    __shared__ unsigned long long table[RSIZE];   // 64 KB static
    unsigned b    = blockIdx.x;                   // (side*NRANGE + r)*NSLICE + s
    unsigned s    = b % NSLICE;
    unsigned rr   = (b / NSLICE) % NRANGE;
    unsigned side = b / (NSLICE * NRANGE);

    for (int i = threadIdx.x; i < RSIZE; i += 1024) table[i] = 0ull;
    __syncthreads();

    unsigned bpg = ((unsigned)nblk + NSLICE - 1) / NSLICE;
    unsigned b0 = s * bpg;
    unsigned b1 = b0 + bpg;
    if (b1 > (unsigned)nblk) b1 = (unsigned)nblk;

    unsigned wid  = threadIdx.x >> 6;             // 16 waves walk independent
    unsigned lane = threadIdx.x & 63;             // sub-segments, stride 16
    unsigned eb = b0 + wid;
    unsigned c_cur = 0, o_cur = 0;
    if (eb < b1) {
        unsigned base = (eb * 2u + side) * NRANGE + rr;
        c_cur = cnts[base];
        o_cur = offs[base];
    }
    while (eb < b1) {
        unsigned eb_n = eb + 16;                  // prefetch next descriptor
        unsigned c_n = 0, o_n = 0;
        if (eb_n < b1) {
            unsigned base_n = (eb_n * 2u + side) * NRANGE + rr;
            c_n = cnts[base_n];
            o_n = offs[base_n];
        }
        const unsigned long long* seg =
            recs + ((size_t)eb * 2 + side) * SEGCAP + o_cur;
        unsigned i = lane;
        for (; i + 64 < c_cur; i += 128) {        // 2 loads in flight
            unsigned long long ra = seg[i];
            unsigned long long rb = seg[i + 64];
            unsigned long long va =  ((ra >> 13) & 0xFFFull)
                                  | (((ra >> 25) & 0xFFFull) << 16)
                                  | (((ra >> 37) & 0xFFFull) << 32)
                                  | (((ra >> 49) & 0xFFFull) << 48);
            unsigned long long vb =  ((rb >> 13) & 0xFFFull)
                                  | (((rb >> 25) & 0xFFFull) << 16)
                                  | (((rb >> 37) & 0xFFFull) << 32)
                                  | (((rb >> 49) & 0xFFFull) << 48);
            atomicAdd(&table[(unsigned)ra & (RSIZE - 1)], va);
            atomicAdd(&table[(unsigned)rb & (RSIZE - 1)], vb);
        }
        if (i < c_cur) {
            unsigned long long ra = seg[i];
            unsigned long long va =  ((ra >> 13) & 0xFFFull)
                                  | (((ra >> 25) & 0xFFFull) << 16)
                                  | (((ra >> 37) & 0xFFFull) << 32)
                                  | (((ra >> 49) & 0xFFFull) << 48);
            atomicAdd(&table[(unsigned)ra & (RSIZE - 1)], va);
        }
        eb = eb_n;
        c_cur = c_n;
        o_cur = o_n;
    }
    __syncthreads();

    unsigned long long* dst = partials + (size_t)b * RSIZE;
    for (int i2 = threadIdx.x; i2 < RSIZE; i2 += 1024) dst[i2] = table[i2];
}

__global__ void merge_bin_kernel(const unsigned long long* __restrict__ partials,
                                 float* __restrict__ up, int n_nodes) {
    int n = blockIdx.x * blockDim.x + threadIdx.x;
    if (n >= n_nodes) return;
    unsigned rr = (unsigned)n >> RBITS;
    unsigned i  = (unsigned)n & (RSIZE - 1);

    const unsigned long long* pn =
        partials + ((size_t)(0 * NRANGE + rr) * NSLICE) * RSIZE + i;
    const unsigned long long* pp =
        partials + ((size_t)(1 * NRANGE + rr) * NSLICE) * RSIZE + i;
    unsigned long long qn = 0, qp = 0;
#pragma unroll
    for (int sl = 0; sl < NSLICE; ++sl) {
        qn += pn[(size_t)sl * RSIZE];
        qp += pp[(size_t)sl * RSIZE];
    }

    float4* dst = (float4*)(up + (size_t)n * 16);
    float4 cur = dst[0];
    float d0 = ((float)(unsigned)( qp        & 0xFFFF) -
                (float)(unsigned)( qn        & 0xFFFF)) * FXP_INV;
    float d1 = ((float)(unsigned)((qp >> 16) & 0xFFFF) -
                (float)(unsigned)((qn >> 16) & 0xFFFF)) * FXP_INV;
    float d2 = ((float)(unsigned)((qp >> 32) & 0xFFFF) -
                (float)(unsigned)((qn >> 32) & 0xFFFF)) * FXP_INV;
    float d3 = ((float)(unsigned)((qp >> 48) & 0xFFFF) -
                (float)(unsigned)((qn >> 48) & 0xFFFF)) * FXP_INV;
    dst[0] = make_float4(cur.x + d0, cur.y + d1, cur.z + d2, cur.w + d3);
}

// ---------- fallback path (R4, proven): packed u64 global atomics ----------

__global__ void edge_atomic_kernel(const float* __restrict__ u,
                                   const float4* __restrict__ binary,
                                   const int* __restrict__ idx1,
                                   const int* __restrict__ idx2,
                                   const float* __restrict__ bw,
                                   unsigned long long* __restrict__ neg,
                                   unsigned long long* __restrict__ pos,
                                   float4* __restrict__ bp,
                                   int n_edges) {
    int e = blockIdx.x * blockDim.x + threadIdx.x;
    if (e >= n_edges) return;
    int n1 = idx1[e], n2 = idx2[e];
    float4 b4 = binary[e];
    float4 a4 = *(const float4*)(u + (size_t)n1 * 16);
    float4 c4 = *(const float4*)(u + (size_t)n2 * 16);
    float a[4]  = {a4.x, a4.y, a4.z, a4.w};
    float bb[4] = {b4.x, b4.y, b4.z, b4.w};
    float c[4]  = {c4.x, c4.y, c4.z, c4.w};
    unsigned long long q1 = 0, q2 = 0;
    float dbv[4];
#pragma unroll
    for (int i = 0; i < 4; ++i) {
        float na = -a[i], nb = -bb[i], cc = c[i];
        float m  = fmaxf(fmaxf(na, nb), cc);
        float e0 = __expf(na - m), e1 = __expf(nb - m), e2 = __expf(cc - m);
        float inv = bw[i] / (e0 + e1 + e2);
        q1 |= (unsigned long long)__float2uint_rn(e0 * inv * FXP_SCALE) << (16 * i);
        q2 |= (unsigned long long)__float2uint_rn(e2 * inv * FXP_SCALE) << (16 * i);
        dbv[i] = bb[i] - e1 * inv;
    }
    atomicAdd(&neg[n1], q1);
    atomicAdd(&pos[n2], q2);
    bp[e] = make_float4(dbv[0], dbv[1], dbv[2], dbv[3]);
}

__global__ void merge_atomic_kernel(const unsigned long long* __restrict__ neg,
                                    const unsigned long long* __restrict__ pos,
                                    float* __restrict__ up, int n_nodes) {
    int n = blockIdx.x * blockDim.x + threadIdx.x;
    if (n >= n_nodes) return;
    unsigned long long qn = neg[n], qp = pos[n];
    float4* dst = (float4*)(up + (size_t)n * 16);
    float4 cur = dst[0];
    float d0 = ((float)(unsigned)( qp        & 0xFFFF) -
                (float)(unsigned)( qn        & 0xFFFF)) * FXP_INV;
    float d1 = ((float)(unsigned)((qp >> 16) & 0xFFFF) -
                (float)(unsigned)((qn >> 16) & 0xFFFF)) * FXP_INV;
    float d2 = ((float)(unsigned)((qp >> 32) & 0xFFFF) -
                (float)(unsigned)((qn >> 32) & 0xFFFF)) * FXP_INV;
    float d3 = ((float)(unsigned)((qp >> 48) & 0xFFFF) -
                (float)(unsigned)((qn >> 48) & 0xFFFF)) * FXP_INV;
    dst[0] = make_float4(cur.x + d0, cur.y + d1, cur.z + d2, cur.w + d3);
}

extern "C" void kernel_launch(void* const* d_in, const int* in_sizes, int n_in,
                              void* d_out, int out_size, void* d_ws, size_t ws_size,
                              hipStream_t stream) {
    const float* unary   = (const float*)d_in[0];
    const float* binary  = (const float*)d_in[1];
    const int*   index1  = (const int*)d_in[2];
    const int*   index2  = (const int*)d_in[3];
    const float* uw      = (const float*)d_in[4];
    const float* bw      = (const float*)d_in[5];

    int n_nodes = in_sizes[0] / 16;
    int n_edges = in_sizes[2];

    float* out = (float*)d_out;
    float* up  = out;                                // n_nodes*16
    float* bp  = out + (size_t)n_nodes * 16;         // n_edges*4

    int nblk = (n_edges + EPB - 1) / EPB;            // 245 @ 2M edges

    // ws layout (fast path): recs | partials | u4 | cnts | offs
    size_t rec_bytes  = (size_t)nblk * 2 * SEGCAP * 8;                   // 32.1 MB
    size_t part_bytes = (size_t)2 * NRANGE * NSLICE * RSIZE * 8;         // 27.26 MB
    size_t u4_bytes   = (size_t)n_nodes * 16;                            // 1.6 MB
    size_t cnt_bytes  = (size_t)nblk * 2 * NRANGE * 4;                   // ~26 KB
    size_t need = rec_bytes + part_bytes + u4_bytes + 2 * cnt_bytes + 256;

    if (ws_size >= need) {
        char* w = (char*)d_ws;
        unsigned long long* recs     = (unsigned long long*)w;
        unsigned long long* partials = (unsigned long long*)(w + rec_bytes);
        float4*   u4   = (float4*)(w + rec_bytes + part_bytes);
        unsigned* cnts = (unsigned*)(w + rec_bytes + part_bytes + u4_bytes);
        unsigned* offs = cnts + (size_t)nblk * 2 * NRANGE;

        unary_kernel<<<(n_nodes + 255) / 256, 256, 0, stream>>>(
            unary, uw, up, u4, n_nodes);
        edge_compute_kernel<<<nblk, 1024, 0, stream>>>(
            u4, (const float4*)binary, index1, index2, bw,
            recs, cnts, offs, (float4*)bp, n_edges);
        bin_kernel<<<2 * NRANGE * NSLICE, 1024, 0, stream>>>(
            recs, cnts, offs, partials, nblk);
        merge_bin_kernel<<<(n_nodes + 255) / 256, 256, 0, stream>>>(
            partials, up, n_nodes);
    } else {
        // R4 fallback: packed u64 atomics (proven)
        unsigned long long* neg = (unsigned long long*)d_ws;
        unsigned long long* pos = neg + n_nodes;
        float4* u4 = (float4*)(pos + n_nodes);
        (void)hipMemsetAsync(neg, 0, (size_t)2 * n_nodes * 8, stream);
        unary_kernel<<<(n_nodes + 255) / 256, 256, 0, stream>>>(
            unary, uw, up, u4, n_nodes);
        edge_atomic_kernel<<<(n_edges + 255) / 256, 256, 0, stream>>>(
            up, (const float4*)binary, index1, index2, bw,
            neg, pos, (float4*)bp, n_edges);
        merge_atomic_kernel<<<(n_nodes + 255) / 256, 256, 0, stream>>>(
            neg, pos, up, n_nodes);
    }
}

// Round 19
// 180.890 us; speedup vs baseline: 1.0408x; 1.0408x over previous
//
#include <hip/hip_runtime.h>
#include <hip/hip_bf16.h>

// RelationalKENN, R16: fix R15's register spill (EPB 8192 retry).
//
// History: R5 bucket sort + LDS binning. R6-R8 block-private slabs: edge
// 102->56us. R9 occupancy probe: edge FLAT. R10 LDS-staged rec stores:
// 159.6. R11 nontemporal: NULL. R12 fused cooperative: CATASTROPHIC.
// R13 NSLICE 16->8: FLAT (bin not BW-bound). R14 EPB 4096: 153.2 BEST
// (segment-latency theory confirmed, +6us). R15 EPB 8192: REGRESSION
// 188us -- launch_bounds(1024,4) capped VGPR at 64, 8-edge carried state
// spilled to scratch (WRITE 63->106MB, FETCH 34->54MB = spill traffic).
// R16: with the 128KB LDS stage only 1 block/CU fits ANYWAY, so the
// VGPR cap bought nothing. Drop min-waves hint (allocator free to ~128+
// VGPR), shrink live state: fused gather+compute loop, bp stored
// immediately, e/valid recomputed at scatter; carried = q1,q2,rank,r
// (~64 VGPRs).
// Predict: VGPR 64->~110-140, WRITE 106->~63MB, FETCH 54->~34MB, edge
// 80->~42-46us, total ->146-153. <150 => knob still pays; ~153 => knob
// exhausted, revert R14 + ceiling arithmetic; WRITE>80MB => still
// spilling, abandon EPB 8192.
//
// Layout: d_out = [ up : n_nodes*16 fp32 | bp : n_edges*4 fp32 ]
// ws = [ recs | partials | u4 | cnts | offs ]

#define NRANGE 13
#define RBITS  13
#define RSIZE  8192            // nodes per range (1 << RBITS)
#define NSLICE 16
#define EPB    8192            // edges per block (1024 threads x 8)
#define SEGCAP 8192            // records per side per block slab
#define FXP_SCALE 2048.0f      // 2^11; magnitudes <= 0.5 -> q <= 1024 (11b)
#define FXP_INV   (1.0f / 2048.0f)

__device__ __forceinline__ void sm2(float xi, float xj, float w,
                                    float& di, float& dj) {
    float na = -xi, b = xj;
    float m  = fmaxf(na, b);
    float e0 = __expf(na - m), e1 = __expf(b - m);
    float inv = w / (e0 + e1);
    di -= e0 * inv;
    dj += e1 * inv;
}

__device__ __forceinline__ void sm3(float xi, float xj, float xk, float w,
                                    float& di, float& dj, float& dk) {
    float na = -xi, b = xj, c = xk;
    float m  = fmaxf(fmaxf(na, b), c);
    float e0 = __expf(na - m), e1 = __expf(b - m), e2 = __expf(c - m);
    float inv = w / (e0 + e1 + e2);
    di -= e0 * inv;
    dj += e1 * inv;
    dk += e2 * inv;
}

__global__ void unary_kernel(const float* __restrict__ x_in,
                             const float* __restrict__ uw,
                             float* __restrict__ up,
                             float4* __restrict__ u4,      // compact cols 0..3
                             int n_nodes) {
    int n = blockIdx.x * blockDim.x + threadIdx.x;
    if (n >= n_nodes) return;

    const float4* xr = (const float4*)(x_in + (size_t)n * 16);
    float4 r0 = xr[0], r1 = xr[1], r2 = xr[2], r3 = xr[3];
    float x[16] = {r0.x, r0.y, r0.z, r0.w,
                   r1.x, r1.y, r1.z, r1.w,
                   r2.x, r2.y, r2.z, r2.w,
                   r3.x, r3.y, r3.z, r3.w};
    float d[16];
#pragma unroll
    for (int i = 0; i < 16; ++i) d[i] = 0.0f;

    sm2(x[0],  x[1],          uw[0], d[0],  d[1]);
    sm2(x[1],  x[2],          uw[1], d[1],  d[2]);
    sm3(x[2],  x[3],  x[4],   uw[2], d[2],  d[3],  d[4]);
    sm2(x[4],  x[5],          uw[3], d[4],  d[5]);
    sm3(x[6],  x[7],  x[8],   uw[4], d[6],  d[7],  d[8]);
    sm2(x[8],  x[9],          uw[5], d[8],  d[9]);
    sm3(x[10], x[11], x[12],  uw[6], d[10], d[11], d[12]);
    sm3(x[13], x[14], x[15],  uw[7], d[13], d[14], d[15]);

    float4* w_up = (float4*)(up + (size_t)n * 16);
    float4 v0 = make_float4(x[0] + d[0], x[1] + d[1], x[2] + d[2], x[3] + d[3]);
    w_up[0] = v0;
#pragma unroll
    for (int i = 1; i < 4; ++i)
        w_up[i] = make_float4(x[4*i]   + d[4*i],   x[4*i+1] + d[4*i+1],
                              x[4*i+2] + d[4*i+2], x[4*i+3] + d[4*i+3]);
    u4[n] = v0;
}

// ---------- fast path ----------

__global__ __launch_bounds__(1024)      // 128KB LDS -> 1 blk/CU regardless;
void edge_compute_kernel(const float4* __restrict__ u4,   // no VGPR cap
                         const float4* __restrict__ binary,
                         const int* __restrict__ idx1,
                         const int* __restrict__ idx2,
                         const float* __restrict__ bw,
                         unsigned long long* __restrict__ recs, // [blk][2][SEGCAP]
                         unsigned* __restrict__ cnts,           // [blk][2][NRANGE]
                         unsigned* __restrict__ offs,           // [blk][2][NRANGE]
                         float4* __restrict__ bp,
                         int n_edges) {
    __shared__ unsigned cnt[2][NRANGE];
    __shared__ unsigned off[2][NRANGE];
    __shared__ __align__(16) unsigned long long stage[2][SEGCAP];  // 128 KB
    int tid = threadIdx.x;
    if (tid < 2 * NRANGE) ((unsigned*)cnt)[tid] = 0;
    __syncthreads();

    float w[4] = {bw[0], bw[1], bw[2], bw[3]};

    // carried state only: ~64 VGPRs (q 32, rank 16, r 16)
    unsigned long long q1[8], q2[8];
    unsigned rank1[8], rank2[8];
    unsigned r1[8], r2[8];

#pragma unroll
    for (int k = 0; k < 8; ++k) {          // fused gather+compute+rank+bp
        int e = blockIdx.x * EPB + k * 1024 + tid;
        bool valid = e < n_edges;
        int ec = valid ? e : 0;
        int i1 = idx1[ec];
        int i2 = idx2[ec];
        float4 a4 = u4[i1];
        float4 c4 = u4[i2];
        float4 b4 = binary[ec];
        float a[4]  = {a4.x, a4.y, a4.z, a4.w};
        float bb[4] = {b4.x, b4.y, b4.z, b4.w};
        float c[4]  = {c4.x, c4.y, c4.z, c4.w};
        unsigned p1[4], p2[4];
        float dbv[4];
#pragma unroll
        for (int i = 0; i < 4; ++i) {
            // clause ([i, 32+i, 16+i], [-1,-1,+1]): sel = [-u1_i, -b_i, u2_i]
            float na = -a[i], nb = -bb[i], cc = c[i];
            float m  = fmaxf(fmaxf(na, nb), cc);
            float e0 = __expf(na - m), e1 = __expf(nb - m), e2 = __expf(cc - m);
            float inv = w[i] / (e0 + e1 + e2);
            p1[i]  = __float2uint_rn(e0 * inv * FXP_SCALE);  // |du1|
            p2[i]  = __float2uint_rn(e2 * inv * FXP_SCALE);  // du2
            dbv[i] = bb[i] - e1 * inv;
        }
        q1[k] = (unsigned long long)(unsigned)(i1 & (RSIZE - 1))
              | ((unsigned long long)p1[0] << 13) | ((unsigned long long)p1[1] << 25)
              | ((unsigned long long)p1[2] << 37) | ((unsigned long long)p1[3] << 49);
        q2[k] = (unsigned long long)(unsigned)(i2 & (RSIZE - 1))
              | ((unsigned long long)p2[0] << 13) | ((unsigned long long)p2[1] << 25)
              | ((unsigned long long)p2[2] << 37) | ((unsigned long long)p2[3] << 49);
        r1[k] = (unsigned)i1 >> RBITS;
        r2[k] = (unsigned)i2 >> RBITS;
        if (valid) {
            rank1[k] = atomicAdd(&cnt[0][r1[k]], 1u);   // LDS atomic rank
            rank2[k] = atomicAdd(&cnt[1][r2[k]], 1u);
            bp[e] = make_float4(dbv[0], dbv[1], dbv[2], dbv[3]);  // store now
        }
    }
    __syncthreads();
    if (tid < 2) {                          // 13-entry exclusive scan per side
        unsigned acc = 0;
#pragma unroll
        for (int r = 0; r < NRANGE; ++r) { off[tid][r] = acc; acc += cnt[tid][r]; }
    }
    __syncthreads();
    if (tid < 2 * NRANGE) {                 // publish counts + offsets
        cnts[(size_t)blockIdx.x * 2 * NRANGE + tid] = ((unsigned*)cnt)[tid];
        offs[(size_t)blockIdx.x * 2 * NRANGE + tid] = ((unsigned*)off)[tid];
    }
#pragma unroll
    for (int k = 0; k < 8; ++k) {           // rank-scatter into LDS stage
        int e = blockIdx.x * EPB + k * 1024 + tid;   // recompute, don't carry
        if (e >= n_edges) continue;
        stage[0][off[0][r1[k]] + rank1[k]] = q1[k];
        stage[1][off[1][r2[k]] + rank2[k]] = q2[k];
    }
    __syncthreads();
    // stream slab out fully coalesced: 1024 thr x 8 x 16B
    ulonglong2* dst = (ulonglong2*)(recs + (size_t)blockIdx.x * 2 * SEGCAP);
    const ulonglong2* s0 = (const ulonglong2*)stage[0];
    const ulonglong2* s1 = (const ulonglong2*)stage[1];
#pragma unroll
    for (int j = 0; j < 4; ++j) {
        dst[j * 1024 + tid]        = s0[j * 1024 + tid];
        dst[4096 + j * 1024 + tid] = s1[j * 1024 + tid];
    }
}

__global__ __launch_bounds__(1024)
void bin_kernel(const unsigned long long* __restrict__ recs,
                const unsigned* __restrict__ cnts,
                const unsigned* __restrict__ offs,
                unsigned long long* __restrict__ partials,
                int nblk) {
    __shared__ unsigned long long table[RSIZE];   // 64 KB static
    unsigned b    = blockIdx.x;                   // (side*NRANGE + r)*NSLICE + s
    unsigned s    = b % NSLICE;
    unsigned rr   = (b / NSLICE) % NRANGE;
    unsigned side = b / (NSLICE * NRANGE);

    for (int i = threadIdx.x; i < RSIZE; i += 1024) table[i] = 0ull;
    __syncthreads();

    unsigned bpg = ((unsigned)nblk + NSLICE - 1) / NSLICE;
    unsigned b0 = s * bpg;
    unsigned b1 = b0 + bpg;
    if (b1 > (unsigned)nblk) b1 = (unsigned)nblk;

    unsigned wid  = threadIdx.x >> 6;             // 16 waves walk independent
    unsigned lane = threadIdx.x & 63;             // sub-segments, stride 16
    unsigned eb = b0 + wid;
    unsigned c_cur = 0, o_cur = 0;
    if (eb < b1) {
        unsigned base = (eb * 2u + side) * NRANGE + rr;
        c_cur = cnts[base];
        o_cur = offs[base];
    }
    while (eb < b1) {
        unsigned eb_n = eb + 16;                  // prefetch next descriptor
        unsigned c_n = 0, o_n = 0;
        if (eb_n < b1) {
            unsigned base_n = (eb_n * 2u + side) * NRANGE + rr;
            c_n = cnts[base_n];
            o_n = offs[base_n];
        }
        const unsigned long long* seg =
            recs + ((size_t)eb * 2 + side) * SEGCAP + o_cur;
        unsigned i = lane;
        for (; i + 64 < c_cur; i += 128) {        // 2 loads in flight
            unsigned long long ra = seg[i];
            unsigned long long rb = seg[i + 64];
            unsigned long long va =  ((ra >> 13) & 0xFFFull)
                                  | (((ra >> 25) & 0xFFFull) << 16)
                                  | (((ra >> 37) & 0xFFFull) << 32)
                                  | (((ra >> 49) & 0xFFFull) << 48);
            unsigned long long vb =  ((rb >> 13) & 0xFFFull)
                                  | (((rb >> 25) & 0xFFFull) << 16)
                                  | (((rb >> 37) & 0xFFFull) << 32)
                                  | (((rb >> 49) & 0xFFFull) << 48);
            atomicAdd(&table[(unsigned)ra & (RSIZE - 1)], va);
            atomicAdd(&table[(unsigned)rb & (RSIZE - 1)], vb);
        }
        if (i < c_cur) {
            unsigned long long ra = seg[i];
            unsigned long long va =  ((ra >> 13) & 0xFFFull)
                                  | (((ra >> 25) & 0xFFFull) << 16)
                                  | (((ra >> 37) & 0xFFFull) << 32)
                                  | (((ra >> 49) & 0xFFFull) << 48);
            atomicAdd(&table[(unsigned)ra & (RSIZE - 1)], va);
        }
        eb = eb_n;
        c_cur = c_n;
        o_cur = o_n;
    }
    __syncthreads();

    unsigned long long* dst = partials + (size_t)b * RSIZE;
    for (int i2 = threadIdx.x; i2 < RSIZE; i2 += 1024) dst[i2] = table[i2];
}

__global__ void merge_bin_kernel(const unsigned long long* __restrict__ partials,
                                 float* __restrict__ up, int n_nodes) {
    int n = blockIdx.x * blockDim.x + threadIdx.x;
    if (n >= n_nodes) return;
    unsigned rr = (unsigned)n >> RBITS;
    unsigned i  = (unsigned)n & (RSIZE - 1);

    const unsigned long long* pn =
        partials + ((size_t)(0 * NRANGE + rr) * NSLICE) * RSIZE + i;
    const unsigned long long* pp =
        partials + ((size_t)(1 * NRANGE + rr) * NSLICE) * RSIZE + i;
    unsigned long long qn = 0, qp = 0;
#pragma unroll
    for (int sl = 0; sl < NSLICE; ++sl) {
        qn += pn[(size_t)sl * RSIZE];
        qp += pp[(size_t)sl * RSIZE];
    }

    float4* dst = (float4*)(up + (size_t)n * 16);
    float4 cur = dst[0];
    float d0 = ((float)(unsigned)( qp        & 0xFFFF) -
                (float)(unsigned)( qn        & 0xFFFF)) * FXP_INV;
    float d1 = ((float)(unsigned)((qp >> 16) & 0xFFFF) -
                (float)(unsigned)((qn >> 16) & 0xFFFF)) * FXP_INV;
    float d2 = ((float)(unsigned)((qp >> 32) & 0xFFFF) -
                (float)(unsigned)((qn >> 32) & 0xFFFF)) * FXP_INV;
    float d3 = ((float)(unsigned)((qp >> 48) & 0xFFFF) -
                (float)(unsigned)((qn >> 48) & 0xFFFF)) * FXP_INV;
    dst[0] = make_float4(cur.x + d0, cur.y + d1, cur.z + d2, cur.w + d3);
}

// ---------- fallback path (R4, proven): packed u64 global atomics ----------

__global__ void edge_atomic_kernel(const float* __restrict__ u,
                                   const float4* __restrict__ binary,
                                   const int* __restrict__ idx1,
                                   const int* __restrict__ idx2,
                                   const float* __restrict__ bw,
                                   unsigned long long* __restrict__ neg,
                                   unsigned long long* __restrict__ pos,
                                   float4* __restrict__ bp,
                                   int n_edges) {
    int e = blockIdx.x * blockDim.x + threadIdx.x;
    if (e >= n_edges) return;
    int n1 = idx1[e], n2 = idx2[e];
    float4 b4 = binary[e];
    float4 a4 = *(const float4*)(u + (size_t)n1 * 16);
    float4 c4 = *(const float4*)(u + (size_t)n2 * 16);
    float a[4]  = {a4.x, a4.y, a4.z, a4.w};
    float bb[4] = {b4.x, b4.y, b4.z, b4.w};
    float c[4]  = {c4.x, c4.y, c4.z, c4.w};
    unsigned long long q1 = 0, q2 = 0;
    float dbv[4];
#pragma unroll
    for (int i = 0; i < 4; ++i) {
        float na = -a[i], nb = -bb[i], cc = c[i];
        float m  = fmaxf(fmaxf(na, nb), cc);
        float e0 = __expf(na - m), e1 = __expf(nb - m), e2 = __expf(cc - m);
        float inv = bw[i] / (e0 + e1 + e2);
        q1 |= (unsigned long long)__float2uint_rn(e0 * inv * FXP_SCALE) << (16 * i);
        q2 |= (unsigned long long)__float2uint_rn(e2 * inv * FXP_SCALE) << (16 * i);
        dbv[i] = bb[i] - e1 * inv;
    }
    atomicAdd(&neg[n1], q1);
    atomicAdd(&pos[n2], q2);
    bp[e] = make_float4(dbv[0], dbv[1], dbv[2], dbv[3]);
}

__global__ void merge_atomic_kernel(const unsigned long long* __restrict__ neg,
                                    const unsigned long long* __restrict__ pos,
                                    float* __restrict__ up, int n_nodes) {
    int n = blockIdx.x * blockDim.x + threadIdx.x;
    if (n >= n_nodes) return;
    unsigned long long qn = neg[n], qp = pos[n];
    float4* dst = (float4*)(up + (size_t)n * 16);
    float4 cur = dst[0];
    float d0 = ((float)(unsigned)( qp        & 0xFFFF) -
                (float)(unsigned)( qn        & 0xFFFF)) * FXP_INV;
    float d1 = ((float)(unsigned)((qp >> 16) & 0xFFFF) -
                (float)(unsigned)((qn >> 16) & 0xFFFF)) * FXP_INV;
    float d2 = ((float)(unsigned)((qp >> 32) & 0xFFFF) -
                (float)(unsigned)((qn >> 32) & 0xFFFF)) * FXP_INV;
    float d3 = ((float)(unsigned)((qp >> 48) & 0xFFFF) -
                (float)(unsigned)((qn >> 48) & 0xFFFF)) * FXP_INV;
    dst[0] = make_float4(cur.x + d0, cur.y + d1, cur.z + d2, cur.w + d3);
}

extern "C" void kernel_launch(void* const* d_in, const int* in_sizes, int n_in,
                              void* d_out, int out_size, void* d_ws, size_t ws_size,
                              hipStream_t stream) {
    const float* unary   = (const float*)d_in[0];
    const float* binary  = (const float*)d_in[1];
    const int*   index1  = (const int*)d_in[2];
    const int*   index2  = (const int*)d_in[3];
    const float* uw      = (const float*)d_in[4];
    const float* bw      = (const float*)d_in[5];

    int n_nodes = in_sizes[0] / 16;
    int n_edges = in_sizes[2];

    float* out = (float*)d_out;
    float* up  = out;                                // n_nodes*16
    float* bp  = out + (size_t)n_nodes * 16;         // n_edges*4

    int nblk = (n_edges + EPB - 1) / EPB;            // 245 @ 2M edges

    // ws layout (fast path): recs | partials | u4 | cnts | offs
    size_t rec_bytes  = (size_t)nblk * 2 * SEGCAP * 8;                   // 32.1 MB
    size_t part_bytes = (size_t)2 * NRANGE * NSLICE * RSIZE * 8;         // 27.26 MB
    size_t u4_bytes   = (size_t)n_nodes * 16;                            // 1.6 MB
    size_t cnt_bytes  = (size_t)nblk * 2 * NRANGE * 4;                   // ~26 KB
    size_t need = rec_bytes + part_bytes + u4_bytes + 2 * cnt_bytes + 256;

    if (ws_size >= need) {
        char* w = (char*)d_ws;
        unsigned long long* recs     = (unsigned long long*)w;
        unsigned long long* partials = (unsigned long long*)(w + rec_bytes);
        float4*   u4   = (float4*)(w + rec_bytes + part_bytes);
        unsigned* cnts = (unsigned*)(w + rec_bytes + part_bytes + u4_bytes);
        unsigned* offs = cnts + (size_t)nblk * 2 * NRANGE;

        unary_kernel<<<(n_nodes + 255) / 256, 256, 0, stream>>>(
            unary, uw, up, u4, n_nodes);
        edge_compute_kernel<<<nblk, 1024, 0, stream>>>(
            u4, (const float4*)binary, index1, index2, bw,
            recs, cnts, offs, (float4*)bp, n_edges);
        bin_kernel<<<2 * NRANGE * NSLICE, 1024, 0, stream>>>(
            recs, cnts, offs, partials, nblk);
        merge_bin_kernel<<<(n_nodes + 255) / 256, 256, 0, stream>>>(
            partials, up, n_nodes);
    } else {
        // R4 fallback: packed u64 atomics (proven)
        unsigned long long* neg = (unsigned long long*)d_ws;
        unsigned long long* pos = neg + n_nodes;
        float4* u4 = (float4*)(pos + n_nodes);
        (void)hipMemsetAsync(neg, 0, (size_t)2 * n_nodes * 8, stream);
        unary_kernel<<<(n_nodes + 255) / 256, 256, 0, stream>>>(
            unary, uw, up, u4, n_nodes);
        edge_atomic_kernel<<<(n_edges + 255) / 256, 256, 0, stream>>>(
            up, (const float4*)binary, index1, index2, bw,
            neg, pos, (float4*)bp, n_edges);
        merge_atomic_kernel<<<(n_nodes + 255) / 256, 256, 0, stream>>>(
            neg, pos, up, n_nodes);
    }
}

// Round 20
// 153.833 us; speedup vs baseline: 1.2238x; 1.1759x over previous
//
#include <hip/hip_runtime.h>
#include <hip/hip_bf16.h>

// RelationalKENN, R17: revert to R14 (proven 153.2) + bin 4-deep loads.
//
// History: R5 bucket sort + LDS binning. R6-R8 block-private slabs: edge
// 102->56us. R9 occupancy probe: edge FLAT. R10 LDS-staged rec stores:
// 159.6. R11 nontemporal: NULL. R12 fused cooperative: CATASTROPHIC.
// R13 NSLICE 16->8: FLAT. R14 EPB 4096 (4 edges/thr, VGPR 48, no spill):
// 153.2 BEST (+6us, segment-latency theory confirmed). R15/R16 EPB 8192:
// REGRESSION 188/181 -- 8-edge carried state spills at the compiler's
// 64-VGPR choice for 1024-thr blocks (WRITE 91-106MB = scratch traffic).
// EPB 8192 abandoned per pre-commit. Lesson: 4 edges/thread is the
// spill-free maximum; EPB 4096 is the segment-knob sweet spot.
// R17: R14 edge byte-identical + ONE change: bin load pipeline 2->4 deep
// (stride 256/iter ~ matches 315-record segments; 2x MLP in hot loop).
// Predict: edge ~44us/VGPR48/WRITE~63MB (revert confirmed); total
// ->147-151 if bin latency-bound on load depth; flat >=152 -> knobs
// exhausted, state ceiling next round.
//
// Layout: d_out = [ up : n_nodes*16 fp32 | bp : n_edges*4 fp32 ]
// ws = [ recs | partials | u4 | cnts | offs ]

#define NRANGE 13
#define RBITS  13
#define RSIZE  8192            // nodes per range (1 << RBITS)
#define NSLICE 16
#define EPB    4096            // edges per block (1024 threads x 4)
#define SEGCAP 4096            // records per side per block slab
#define FXP_SCALE 2048.0f      // 2^11; magnitudes <= 0.5 -> q <= 1024 (11b)
#define FXP_INV   (1.0f / 2048.0f)

__device__ __forceinline__ void sm2(float xi, float xj, float w,
                                    float& di, float& dj) {
    float na = -xi, b = xj;
    float m  = fmaxf(na, b);
    float e0 = __expf(na - m), e1 = __expf(b - m);
    float inv = w / (e0 + e1);
    di -= e0 * inv;
    dj += e1 * inv;
}

__device__ __forceinline__ void sm3(float xi, float xj, float xk, float w,
                                    float& di, float& dj, float& dk) {
    float na = -xi, b = xj, c = xk;
    float m  = fmaxf(fmaxf(na, b), c);
    float e0 = __expf(na - m), e1 = __expf(b - m), e2 = __expf(c - m);
    float inv = w / (e0 + e1 + e2);
    di -= e0 * inv;
    dj += e1 * inv;
    dk += e2 * inv;
}

__device__ __forceinline__ unsigned long long expand12(unsigned long long r) {
    return  ((r >> 13) & 0xFFFull)
         | (((r >> 25) & 0xFFFull) << 16)
         | (((r >> 37) & 0xFFFull) << 32)
         | (((r >> 49) & 0xFFFull) << 48);
}

__global__ void unary_kernel(const float* __restrict__ x_in,
                             const float* __restrict__ uw,
                             float* __restrict__ up,
                             float4* __restrict__ u4,      // compact cols 0..3
                             int n_nodes) {
    int n = blockIdx.x * blockDim.x + threadIdx.x;
    if (n >= n_nodes) return;

    const float4* xr = (const float4*)(x_in + (size_t)n * 16);
    float4 r0 = xr[0], r1 = xr[1], r2 = xr[2], r3 = xr[3];
    float x[16] = {r0.x, r0.y, r0.z, r0.w,
                   r1.x, r1.y, r1.z, r1.w,
                   r2.x, r2.y, r2.z, r2.w,
                   r3.x, r3.y, r3.z, r3.w};
    float d[16];
#pragma unroll
    for (int i = 0; i < 16; ++i) d[i] = 0.0f;

    sm2(x[0],  x[1],          uw[0], d[0],  d[1]);
    sm2(x[1],  x[2],          uw[1], d[1],  d[2]);
    sm3(x[2],  x[3],  x[4],   uw[2], d[2],  d[3],  d[4]);
    sm2(x[4],  x[5],          uw[3], d[4],  d[5]);
    sm3(x[6],  x[7],  x[8],   uw[4], d[6],  d[7],  d[8]);
    sm2(x[8],  x[9],          uw[5], d[8],  d[9]);
    sm3(x[10], x[11], x[12],  uw[6], d[10], d[11], d[12]);
    sm3(x[13], x[14], x[15],  uw[7], d[13], d[14], d[15]);

    float4* w_up = (float4*)(up + (size_t)n * 16);
    float4 v0 = make_float4(x[0] + d[0], x[1] + d[1], x[2] + d[2], x[3] + d[3]);
    w_up[0] = v0;
#pragma unroll
    for (int i = 1; i < 4; ++i)
        w_up[i] = make_float4(x[4*i]   + d[4*i],   x[4*i+1] + d[4*i+1],
                              x[4*i+2] + d[4*i+2], x[4*i+3] + d[4*i+3]);
    u4[n] = v0;
}

// ---------- fast path ----------

__global__ __launch_bounds__(1024, 4)
void edge_compute_kernel(const float4* __restrict__ u4,
                         const float4* __restrict__ binary,
                         const int* __restrict__ idx1,
                         const int* __restrict__ idx2,
                         const float* __restrict__ bw,
                         unsigned long long* __restrict__ recs, // [blk][2][SEGCAP]
                         unsigned* __restrict__ cnts,           // [blk][2][NRANGE]
                         unsigned* __restrict__ offs,           // [blk][2][NRANGE]
                         float4* __restrict__ bp,
                         int n_edges) {
    __shared__ unsigned cnt[2][NRANGE];
    __shared__ unsigned off[2][NRANGE];
    __shared__ __align__(16) unsigned long long stage[2][SEGCAP];  // 64 KB
    int tid = threadIdx.x;
    if (tid < 2 * NRANGE) ((unsigned*)cnt)[tid] = 0;
    __syncthreads();

    float w[4] = {bw[0], bw[1], bw[2], bw[3]};

    int e[4]; bool valid[4];
    int i1[4], i2[4], r1[4], r2[4];
    unsigned rank1[4], rank2[4];
    unsigned long long q1[4], q2[4];
    float4 b4[4], a4[4], c4[4], dbv4[4];

#pragma unroll
    for (int k = 0; k < 4; ++k) {
        e[k] = blockIdx.x * EPB + k * 1024 + tid;
        valid[k] = e[k] < n_edges;
        int ec = valid[k] ? e[k] : 0;
        i1[k] = idx1[ec];
        i2[k] = idx2[ec];
    }
#pragma unroll
    for (int k = 0; k < 4; ++k) {          // 8 gathers + 4 streams in flight
        a4[k] = u4[i1[k]];
        c4[k] = u4[i2[k]];
        b4[k] = binary[valid[k] ? e[k] : 0];
    }

#pragma unroll
    for (int k = 0; k < 4; ++k) {
        float a[4]  = {a4[k].x, a4[k].y, a4[k].z, a4[k].w};
        float bb[4] = {b4[k].x, b4[k].y, b4[k].z, b4[k].w};
        float c[4]  = {c4[k].x, c4[k].y, c4[k].z, c4[k].w};
        unsigned p1[4], p2[4];
        float dbv[4];
#pragma unroll
        for (int i = 0; i < 4; ++i) {
            // clause ([i, 32+i, 16+i], [-1,-1,+1]): sel = [-u1_i, -b_i, u2_i]
            float na = -a[i], nb = -bb[i], cc = c[i];
            float m  = fmaxf(fmaxf(na, nb), cc);
            float e0 = __expf(na - m), e1 = __expf(nb - m), e2 = __expf(cc - m);
            float inv = w[i] / (e0 + e1 + e2);
            p1[i]  = __float2uint_rn(e0 * inv * FXP_SCALE);  // |du1|
            p2[i]  = __float2uint_rn(e2 * inv * FXP_SCALE);  // du2
            dbv[i] = bb[i] - e1 * inv;
        }
        q1[k] = (unsigned long long)(unsigned)(i1[k] & (RSIZE - 1))
              | ((unsigned long long)p1[0] << 13) | ((unsigned long long)p1[1] << 25)
              | ((unsigned long long)p1[2] << 37) | ((unsigned long long)p1[3] << 49);
        q2[k] = (unsigned long long)(unsigned)(i2[k] & (RSIZE - 1))
              | ((unsigned long long)p2[0] << 13) | ((unsigned long long)p2[1] << 25)
              | ((unsigned long long)p2[2] << 37) | ((unsigned long long)p2[3] << 49);
        dbv4[k] = make_float4(dbv[0], dbv[1], dbv[2], dbv[3]);
        r1[k] = i1[k] >> RBITS;
        r2[k] = i2[k] >> RBITS;
        if (valid[k]) {
            rank1[k] = atomicAdd(&cnt[0][r1[k]], 1u);   // LDS atomic rank
            rank2[k] = atomicAdd(&cnt[1][r2[k]], 1u);
        }
    }
    __syncthreads();
    if (tid < 2) {                          // 13-entry exclusive scan per side
        unsigned acc = 0;
#pragma unroll
        for (int r = 0; r < NRANGE; ++r) { off[tid][r] = acc; acc += cnt[tid][r]; }
    }
    __syncthreads();
    if (tid < 2 * NRANGE) {                 // publish counts + offsets
        cnts[(size_t)blockIdx.x * 2 * NRANGE + tid] = ((unsigned*)cnt)[tid];
        offs[(size_t)blockIdx.x * 2 * NRANGE + tid] = ((unsigned*)off)[tid];
    }
#pragma unroll
    for (int k = 0; k < 4; ++k) {           // rank-scatter into LDS stage
        if (!valid[k]) continue;
        stage[0][off[0][r1[k]] + rank1[k]] = q1[k];
        stage[1][off[1][r2[k]] + rank2[k]] = q2[k];
        bp[e[k]] = dbv4[k];
    }
    __syncthreads();
    // stream slab out fully coalesced: 1024 thr x 4 x 16B
    ulonglong2* dst = (ulonglong2*)(recs + (size_t)blockIdx.x * 2 * SEGCAP);
    const ulonglong2* s0 = (const ulonglong2*)stage[0];
    const ulonglong2* s1 = (const ulonglong2*)stage[1];
    dst[tid]        = s0[tid];
    dst[1024 + tid] = s0[1024 + tid];
    dst[2048 + tid] = s1[tid];
    dst[3072 + tid] = s1[1024 + tid];
}

__global__ __launch_bounds__(1024)
void bin_kernel(const unsigned long long* __restrict__ recs,
                const unsigned* __restrict__ cnts,
                const unsigned* __restrict__ offs,
                unsigned long long* __restrict__ partials,
                int nblk) {
    __shared__ unsigned long long table[RSIZE];   // 64 KB static
    unsigned b    = blockIdx.x;                   // (side*NRANGE + r)*NSLICE + s
    unsigned s    = b % NSLICE;
    unsigned rr   = (b / NSLICE) % NRANGE;
    unsigned side = b / (NSLICE * NRANGE);

    for (int i = threadIdx.x; i < RSIZE; i += 1024) table[i] = 0ull;
    __syncthreads();

    unsigned bpg = ((unsigned)nblk + NSLICE - 1) / NSLICE;
    unsigned b0 = s * bpg;
    unsigned b1 = b0 + bpg;
    if (b1 > (unsigned)nblk) b1 = (unsigned)nblk;

    unsigned wid  = threadIdx.x >> 6;             // 16 waves walk independent
    unsigned lane = threadIdx.x & 63;             // sub-segments, stride 16
    unsigned eb = b0 + wid;
    unsigned c_cur = 0, o_cur = 0;
    if (eb < b1) {
        unsigned base = (eb * 2u + side) * NRANGE + rr;
        c_cur = cnts[base];
        o_cur = offs[base];
    }
    while (eb < b1) {
        unsigned eb_n = eb + 16;                  // prefetch next descriptor
        unsigned c_n = 0, o_n = 0;
        if (eb_n < b1) {
            unsigned base_n = (eb_n * 2u + side) * NRANGE + rr;
            c_n = cnts[base_n];
            o_n = offs[base_n];
        }
        const unsigned long long* seg =
            recs + ((size_t)eb * 2 + side) * SEGCAP + o_cur;
        unsigned i = lane;
        for (; i + 192 < c_cur; i += 256) {       // 4 loads in flight
            unsigned long long ra = seg[i];
            unsigned long long rb = seg[i + 64];
            unsigned long long rc = seg[i + 128];
            unsigned long long rd = seg[i + 192];
            atomicAdd(&table[(unsigned)ra & (RSIZE - 1)], expand12(ra));
            atomicAdd(&table[(unsigned)rb & (RSIZE - 1)], expand12(rb));
            atomicAdd(&table[(unsigned)rc & (RSIZE - 1)], expand12(rc));
            atomicAdd(&table[(unsigned)rd & (RSIZE - 1)], expand12(rd));
        }
        for (; i + 64 < c_cur; i += 128) {        // pair tail
            unsigned long long ra = seg[i];
            unsigned long long rb = seg[i + 64];
            atomicAdd(&table[(unsigned)ra & (RSIZE - 1)], expand12(ra));
            atomicAdd(&table[(unsigned)rb & (RSIZE - 1)], expand12(rb));
        }
        if (i < c_cur) {
            unsigned long long ra = seg[i];
            atomicAdd(&table[(unsigned)ra & (RSIZE - 1)], expand12(ra));
        }
        eb = eb_n;
        c_cur = c_n;
        o_cur = o_n;
    }
    __syncthreads();

    unsigned long long* dst = partials + (size_t)b * RSIZE;
    for (int i2 = threadIdx.x; i2 < RSIZE; i2 += 1024) dst[i2] = table[i2];
}

__global__ void merge_bin_kernel(const unsigned long long* __restrict__ partials,
                                 float* __restrict__ up, int n_nodes) {
    int n = blockIdx.x * blockDim.x + threadIdx.x;
    if (n >= n_nodes) return;
    unsigned rr = (unsigned)n >> RBITS;
    unsigned i  = (unsigned)n & (RSIZE - 1);

    const unsigned long long* pn =
        partials + ((size_t)(0 * NRANGE + rr) * NSLICE) * RSIZE + i;
    const unsigned long long* pp =
        partials + ((size_t)(1 * NRANGE + rr) * NSLICE) * RSIZE + i;
    unsigned long long qn = 0, qp = 0;
#pragma unroll
    for (int sl = 0; sl < NSLICE; ++sl) {
        qn += pn[(size_t)sl * RSIZE];
        qp += pp[(size_t)sl * RSIZE];
    }

    float4* dst = (float4*)(up + (size_t)n * 16);
    float4 cur = dst[0];
    float d0 = ((float)(unsigned)( qp        & 0xFFFF) -
                (float)(unsigned)( qn        & 0xFFFF)) * FXP_INV;
    float d1 = ((float)(unsigned)((qp >> 16) & 0xFFFF) -
                (float)(unsigned)((qn >> 16) & 0xFFFF)) * FXP_INV;
    float d2 = ((float)(unsigned)((qp >> 32) & 0xFFFF) -
                (float)(unsigned)((qn >> 32) & 0xFFFF)) * FXP_INV;
    float d3 = ((float)(unsigned)((qp >> 48) & 0xFFFF) -
                (float)(unsigned)((qn >> 48) & 0xFFFF)) * FXP_INV;
    dst[0] = make_float4(cur.x + d0, cur.y + d1, cur.z + d2, cur.w + d3);
}

// ---------- fallback path (R4, proven): packed u64 global atomics ----------

__global__ void edge_atomic_kernel(const float* __restrict__ u,
                                   const float4* __restrict__ binary,
                                   const int* __restrict__ idx1,
                                   const int* __restrict__ idx2,
                                   const float* __restrict__ bw,
                                   unsigned long long* __restrict__ neg,
                                   unsigned long long* __restrict__ pos,
                                   float4* __restrict__ bp,
                                   int n_edges) {
    int e = blockIdx.x * blockDim.x + threadIdx.x;
    if (e >= n_edges) return;
    int n1 = idx1[e], n2 = idx2[e];
    float4 b4 = binary[e];
    float4 a4 = *(const float4*)(u + (size_t)n1 * 16);
    float4 c4 = *(const float4*)(u + (size_t)n2 * 16);
    float a[4]  = {a4.x, a4.y, a4.z, a4.w};
    float bb[4] = {b4.x, b4.y, b4.z, b4.w};
    float c[4]  = {c4.x, c4.y, c4.z, c4.w};
    unsigned long long q1 = 0, q2 = 0;
    float dbv[4];
#pragma unroll
    for (int i = 0; i < 4; ++i) {
        float na = -a[i], nb = -bb[i], cc = c[i];
        float m  = fmaxf(fmaxf(na, nb), cc);
        float e0 = __expf(na - m), e1 = __expf(nb - m), e2 = __expf(cc - m);
        float inv = bw[i] / (e0 + e1 + e2);
        q1 |= (unsigned long long)__float2uint_rn(e0 * inv * FXP_SCALE) << (16 * i);
        q2 |= (unsigned long long)__float2uint_rn(e2 * inv * FXP_SCALE) << (16 * i);
        dbv[i] = bb[i] - e1 * inv;
    }
    atomicAdd(&neg[n1], q1);
    atomicAdd(&pos[n2], q2);
    bp[e] = make_float4(dbv[0], dbv[1], dbv[2], dbv[3]);
}

__global__ void merge_atomic_kernel(const unsigned long long* __restrict__ neg,
                                    const unsigned long long* __restrict__ pos,
                                    float* __restrict__ up, int n_nodes) {
    int n = blockIdx.x * blockDim.x + threadIdx.x;
    if (n >= n_nodes) return;
    unsigned long long qn = neg[n], qp = pos[n];
    float4* dst = (float4*)(up + (size_t)n * 16);
    float4 cur = dst[0];
    float d0 = ((float)(unsigned)( qp        & 0xFFFF) -
                (float)(unsigned)( qn        & 0xFFFF)) * FXP_INV;
    float d1 = ((float)(unsigned)((qp >> 16) & 0xFFFF) -
                (float)(unsigned)((qn >> 16) & 0xFFFF)) * FXP_INV;
    float d2 = ((float)(unsigned)((qp >> 32) & 0xFFFF) -
                (float)(unsigned)((qn >> 32) & 0xFFFF)) * FXP_INV;
    float d3 = ((float)(unsigned)((qp >> 48) & 0xFFFF) -
                (float)(unsigned)((qn >> 48) & 0xFFFF)) * FXP_INV;
    dst[0] = make_float4(cur.x + d0, cur.y + d1, cur.z + d2, cur.w + d3);
}

extern "C" void kernel_launch(void* const* d_in, const int* in_sizes, int n_in,
                              void* d_out, int out_size, void* d_ws, size_t ws_size,
                              hipStream_t stream) {
    const float* unary   = (const float*)d_in[0];
    const float* binary  = (const float*)d_in[1];
    const int*   index1  = (const int*)d_in[2];
    const int*   index2  = (const int*)d_in[3];
    const float* uw      = (const float*)d_in[4];
    const float* bw      = (const float*)d_in[5];

    int n_nodes = in_sizes[0] / 16;
    int n_edges = in_sizes[2];

    float* out = (float*)d_out;
    float* up  = out;                                // n_nodes*16
    float* bp  = out + (size_t)n_nodes * 16;         // n_edges*4

    int nblk = (n_edges + EPB - 1) / EPB;            // 489 @ 2M edges

    // ws layout (fast path): recs | partials | u4 | cnts | offs
    size_t rec_bytes  = (size_t)nblk * 2 * SEGCAP * 8;                   // 32.05 MB
    size_t part_bytes = (size_t)2 * NRANGE * NSLICE * RSIZE * 8;         // 27.26 MB
    size_t u4_bytes   = (size_t)n_nodes * 16;                            // 1.6 MB
    size_t cnt_bytes  = (size_t)nblk * 2 * NRANGE * 4;                   // ~51 KB
    size_t need = rec_bytes + part_bytes + u4_bytes + 2 * cnt_bytes + 256;

    if (ws_size >= need) {
        char* w = (char*)d_ws;
        unsigned long long* recs     = (unsigned long long*)w;
        unsigned long long* partials = (unsigned long long*)(w + rec_bytes);
        float4*   u4   = (float4*)(w + rec_bytes + part_bytes);
        unsigned* cnts = (unsigned*)(w + rec_bytes + part_bytes + u4_bytes);
        unsigned* offs = cnts + (size_t)nblk * 2 * NRANGE;

        unary_kernel<<<(n_nodes + 255) / 256, 256, 0, stream>>>(
            unary, uw, up, u4, n_nodes);
        edge_compute_kernel<<<nblk, 1024, 0, stream>>>(
            u4, (const float4*)binary, index1, index2, bw,
            recs, cnts, offs, (float4*)bp, n_edges);
        bin_kernel<<<2 * NRANGE * NSLICE, 1024, 0, stream>>>(
            recs, cnts, offs, partials, nblk);
        merge_bin_kernel<<<(n_nodes + 255) / 256, 256, 0, stream>>>(
            partials, up, n_nodes);
    } else {
        // R4 fallback: packed u64 atomics (proven)
        unsigned long long* neg = (unsigned long long*)d_ws;
        unsigned long long* pos = neg + n_nodes;
        float4* u4 = (float4*)(pos + n_nodes);
        (void)hipMemsetAsync(neg, 0, (size_t)2 * n_nodes * 8, stream);
        unary_kernel<<<(n_nodes + 255) / 256, 256, 0, stream>>>(
            unary, uw, up, u4, n_nodes);
        edge_atomic_kernel<<<(n_edges + 255) / 256, 256, 0, stream>>>(
            up, (const float4*)binary, index1, index2, bw,
            neg, pos, (float4*)bp, n_edges);
        merge_atomic_kernel<<<(n_nodes + 255) / 256, 256, 0, stream>>>(
            neg, pos, up, n_nodes);
    }
}